// Round 18
// baseline (199.332 us; speedup 1.0000x reference)
//
#include <hip/hip_runtime.h>
#include <math.h>

#define NTOK 8192
#define NCODE 8192
#define DIMD 256
#define NSPLIT 4
#define KQ (NCODE / NSPLIT)     // 2048 codes per pass1 quarter
#define NQ (NTOK / NSPLIT)      // 2048 tokens per pass2 quarter
#define SCALE2 288.5390081777927f   // 200 * log2(e)
#define LN2F 0.6931471805599453f

typedef _Float16 f16;
typedef _Float16 f16x8 __attribute__((ext_vector_type(8)));
typedef float f32x4 __attribute__((ext_vector_type(4)));

#define WAIT_VM(N) asm volatile("s_waitcnt vmcnt(" #N ")" ::: "memory")
#define BAR() __builtin_amdgcn_s_barrier()

__device__ __forceinline__ float fexp2(float x) {
    return __builtin_amdgcn_exp2f(x);   // v_exp_f32 (2^x)
}
__device__ __forceinline__ float4 ldg4(const float* p) {
    return *reinterpret_cast<const float4*>(p);
}
__device__ __forceinline__ unsigned short f2h(float x) {
    f16 h = (f16)x;
    return __builtin_bit_cast(unsigned short, h);
}
__device__ __forceinline__ void gl16(const void* g, void* l) {
    __builtin_amdgcn_global_load_lds(
        (const __attribute__((address_space(1))) unsigned int*)g,
        (__attribute__((address_space(3))) unsigned int*)l, 16, 0, 0);
}

// ---------------------------------------------------------------- prep_all
// blocks 0..511: normalize z -> zf16 + zn (f32) + zinv ; 512..2559: embedding
__global__ __launch_bounds__(256) void prep_all(const float* __restrict__ z,
    const float* __restrict__ e, f16* __restrict__ zf, float* __restrict__ zn,
    f16* __restrict__ ef, float* __restrict__ zinvp, float* __restrict__ esq,
    float* __restrict__ einvp, float* __restrict__ scal)
{
    if (blockIdx.x < 512) {
        int bh = blockIdx.x;
        int c  = threadIdx.x;
        const float* src = z + (size_t)(bh >> 4) * 65536 + (size_t)c * 256 + (size_t)(bh & 15) * 16;
        float v[16];
        float4 t0 = ldg4(src + 0), t1 = ldg4(src + 4), t2 = ldg4(src + 8), t3 = ldg4(src + 12);
        v[0]=t0.x; v[1]=t0.y; v[2]=t0.z; v[3]=t0.w;
        v[4]=t1.x; v[5]=t1.y; v[6]=t1.z; v[7]=t1.w;
        v[8]=t2.x; v[9]=t2.y; v[10]=t2.z; v[11]=t2.w;
        v[12]=t3.x; v[13]=t3.y; v[14]=t3.z; v[15]=t3.w;
        float sq[16];
#pragma unroll
        for (int w = 0; w < 16; ++w) sq[w] = v[w] * v[w];
#pragma unroll
        for (int o = 32; o > 0; o >>= 1) {
#pragma unroll
            for (int w = 0; w < 16; ++w) sq[w] += __shfl_xor(sq[w], o, 64);
        }
        __shared__ float part[4][16];
        __shared__ float invS[16];
        int wave = c >> 6, lane = c & 63;
        if (lane == 0) {
#pragma unroll
            for (int w = 0; w < 16; ++w) part[wave][w] = sq[w];
        }
        __syncthreads();
        if (c < 16) {
            float s = part[0][c] + part[1][c] + part[2][c] + part[3][c];
            float iv = 1.0f / sqrtf(s + 1e-12f);
            invS[c] = iv;
            zinvp[bh * 16 + c] = iv;
        }
        __syncthreads();
#pragma unroll
        for (int w = 0; w < 16; ++w) {
            float nv = v[w] * invS[w];
            zf[(size_t)(bh * 16 + w) * DIMD + c] = (f16)nv;
            zn[(size_t)(bh * 16 + w) * DIMD + c] = nv;
        }
    } else {
        if (blockIdx.x == 512 && threadIdx.x < 2) scal[threadIdx.x] = 0.0f;
        int row  = (int)(blockIdx.x - 512) * 4 + (threadIdx.x >> 6);
        int lane = threadIdx.x & 63;
        float4 v = ldg4(e + (size_t)row * DIMD + lane * 4);
        float ss = v.x*v.x + v.y*v.y + v.z*v.z + v.w*v.w;
#pragma unroll
        for (int o = 32; o > 0; o >>= 1) ss += __shfl_xor(ss, o, 64);
        float inv = 1.0f / sqrtf(ss + 1e-12f);
        float w4[4] = { v.x*inv, v.y*inv, v.z*inv, v.w*inv };
        ushort4 pk;
        pk.x = f2h(w4[0]); pk.y = f2h(w4[1]); pk.z = f2h(w4[2]); pk.w = f2h(w4[3]);
        *reinterpret_cast<ushort4*>(ef + (size_t)row * DIMD + lane * 4) = pk;
        float s2 = w4[0]*w4[0] + w4[1]*w4[1] + w4[2]*w4[2] + w4[3]*w4[3];
#pragma unroll
        for (int o = 32; o > 0; o >>= 1) s2 += __shfl_xor(s2, o, 64);
        if (lane == 0) { esq[row] = s2; einvp[row] = inv; }
    }
}

// ---------------------------------------------------------------- pass1
// D[code][token] f16 MFMA GEMM. Base-2 logits (esq dropped from ranking;
// fixup exact). Per-lane online softmax (defer-max THR=40) + per-lane TOP-1.
// 4-slot LDS ring, counted vmcnt(4). T15: two acc sets pA/pB; tile t's
// epilogue deferred into chunks dc=0,1 of tile t+1 (overlaps MFMA latency).
__global__ __launch_bounds__(512, 4) void pass1(
    const f16* __restrict__ ef, const f16* __restrict__ zf,
    float* __restrict__ pms, int* __restrict__ pi1, int* __restrict__ pi2,
    float* __restrict__ psv, float* __restrict__ puv)
{
    __shared__ __align__(16) char sBuf[4][16384];

    const int tid = threadIdx.x;
    const int lane = tid & 63;
    const int wv = tid >> 6;
    const int tg = wv >> 2;        // token half (32 tokens)
    const int cg = wv & 3;         // code quarter of the 128-code tile
    const int tkbase = (int)(blockIdx.x >> 2) * 64;
    const int quarter = blockIdx.x & 3;
    const int kbase = quarter * KQ;

    f16x8 zfr[2][8];   // this wave's 32 tokens x 256 dims (64 VGPR)

    // ---- prologue: stage 64 tokens (swizzled 32KB = slots 0,1), read own half
    {
        char* sb0 = (char*)sBuf;
#pragma unroll
        for (int i = 0; i < 4; ++i) {
            int row = wv * 8 + i * 2 + (lane >> 5);
            int chunk = (lane & 31) ^ (row & 7);
            gl16(zf + (size_t)(tkbase + row) * DIMD + chunk * 8,
                 sb0 + wv * 4096 + i * 1024 + lane * 16);
        }
        __syncthreads();
#pragma unroll
        for (int tf = 0; tf < 2; ++tf) {
            int row = tg * 32 + tf * 16 + (lane & 15);
#pragma unroll
            for (int ks = 0; ks < 8; ++ks) {
                int slot = (ks * 4 + (lane >> 4)) ^ (row & 7);
                zfr[tf][ks] = *(const f16x8*)(sb0 + row * 512 + slot * 16);
            }
        }
        __syncthreads();
    }

    // hoisted loop-invariant offsets
    const int rowE0 = cg * 32 + (lane & 15);
    const int slotE0 = (lane >> 4) ^ (lane & 7);
    const int slotE1 = (4 + (lane >> 4)) ^ (lane & 7);
    const int offE00 = rowE0 * 128 + slotE0 * 16;
    const int offE01 = rowE0 * 128 + slotE1 * 16;
    const int offE10 = offE00 + 16 * 128;
    const int offE11 = offE01 + 16 * 128;
    const int dstLaneOff = wv * 2048 + lane * 16;
    const f16* efBase = ef + (size_t)kbase * DIMD
                        + (size_t)(wv * 16 + (lane >> 3)) * DIMD
                        + ((lane & 7) ^ ((lane >> 3) & 7)) * 8;

    auto STAGE = [&](int c) {
        char* dst = (char*)sBuf + (c & 3) * 16384 + dstLaneOff;
        const f16* src = efBase + (size_t)(c >> 2) * (128 * DIMD) + (c & 3) * 64;
        gl16(src, dst);
        gl16(src + 8 * DIMD, dst + 1024);
    };

    const f32x4 zero4 = {0.f, 0.f, 0.f, 0.f};
    f32x4 pA[2][2], pB[2][2];

    // per-lane state: softmax ref mS (base-2, defer-max), s,u; top-1 raw-dot
    float mS[2], sS[2], uU[2], m1[2], m2[2];
    int i1[2], i2[2];
#pragma unroll
    for (int t = 0; t < 2; ++t) {
        mS[t] = -3.0e38f; sS[t] = 0.f; uU[t] = 0.f;
        m1[t] = -3.0e38f; m2[t] = -3.0e38f; i1[t] = 0; i2[t] = 0;
    }

    auto BODY = [&](f32x4 (&A)[2][2], int c, f16x8 z00, f16x8 z01,
                    f16x8 z10, f16x8 z11, bool first) {
        const char* sb = (const char*)sBuf + (c & 3) * 16384;
        {
            f16x8 e0 = *(const f16x8*)(sb + offE00);
            f16x8 e1 = *(const f16x8*)(sb + offE10);
            A[0][0] = __builtin_amdgcn_mfma_f32_16x16x32_f16(e0, z00, first ? zero4 : A[0][0], 0, 0, 0);
            A[0][1] = __builtin_amdgcn_mfma_f32_16x16x32_f16(e0, z10, first ? zero4 : A[0][1], 0, 0, 0);
            A[1][0] = __builtin_amdgcn_mfma_f32_16x16x32_f16(e1, z00, first ? zero4 : A[1][0], 0, 0, 0);
            A[1][1] = __builtin_amdgcn_mfma_f32_16x16x32_f16(e1, z10, first ? zero4 : A[1][1], 0, 0, 0);
        }
        {
            f16x8 e0 = *(const f16x8*)(sb + offE01);
            f16x8 e1 = *(const f16x8*)(sb + offE11);
            A[0][0] = __builtin_amdgcn_mfma_f32_16x16x32_f16(e0, z01, A[0][0], 0, 0, 0);
            A[0][1] = __builtin_amdgcn_mfma_f32_16x16x32_f16(e0, z11, A[0][1], 0, 0, 0);
            A[1][0] = __builtin_amdgcn_mfma_f32_16x16x32_f16(e1, z01, A[1][0], 0, 0, 0);
            A[1][1] = __builtin_amdgcn_mfma_f32_16x16x32_f16(e1, z11, A[1][1], 0, 0, 0);
        }
    };

    // epilogue for ONE tf of a completed tile's acc set
    auto EPI = [&](f32x4 (&A)[2][2], int tile, int tf) {
        const int codeB = kbase + tile * 128 + cg * 32 + (lane >> 4) * 4;
#pragma unroll
        for (int j = 0; j < 8; ++j) {
            float x = A[j >> 2][tf][j & 3];
            int cid = codeB + (j >> 2) * 16 + (j & 3);
            bool c1 = x > m1[tf];
            i1[tf] = c1 ? cid : i1[tf];
            m1[tf] = c1 ? x : m1[tf];
        }
        float l2 = SCALE2 * m1[tf];
        if (l2 > mS[tf] + 40.f) {
            float dm = mS[tf] - l2;
            float al = fexp2(dm);
            uU[tf] = al * (uU[tf] + sS[tf] * dm);
            sS[tf] = al * sS[tf];
            mS[tf] = l2;
        }
        float ps = 0.f, pu = 0.f;
        float nm = -mS[tf];
#pragma unroll
        for (int j = 0; j < 8; ++j) {
            float xm = fmaf(SCALE2, A[j >> 2][tf][j & 3], nm);
            float e2 = fexp2(xm);
            ps += e2;
            pu = fmaf(e2, xm, pu);
        }
        sS[tf] += ps;
        uU[tf] += pu;
    };

    STAGE(0); STAGE(1); STAGE(2);

    // tile pairs 0..13 (even->pA, odd->pB); EPI of previous tile at dc 0,1
    for (int tp = 0; tp < 7; ++tp) {
        const int t0 = tp * 2, t1 = t0 + 1;
#pragma unroll
        for (int dc = 0; dc < 4; ++dc) {
            const int c = t0 * 4 + dc;
            WAIT_VM(4); BAR(); STAGE(c + 3);
            BODY(pA, c, zfr[0][dc*2], zfr[0][dc*2+1], zfr[1][dc*2], zfr[1][dc*2+1], dc == 0);
            if (tp > 0 && dc < 2) EPI(pB, t0 - 1, dc);
        }
#pragma unroll
        for (int dc = 0; dc < 4; ++dc) {
            const int c = t1 * 4 + dc;
            WAIT_VM(4); BAR(); STAGE(c + 3);
            BODY(pB, c, zfr[0][dc*2], zfr[0][dc*2+1], zfr[1][dc*2], zfr[1][dc*2+1], dc == 0);
            if (dc < 2) EPI(pA, t0, dc);
        }
    }
    // tile 14 (pA): chunks 56..59, STAGE 59..62
#pragma unroll
    for (int dc = 0; dc < 4; ++dc) {
        const int c = 56 + dc;
        WAIT_VM(4); BAR(); STAGE(c + 3);
        BODY(pA, c, zfr[0][dc*2], zfr[0][dc*2+1], zfr[1][dc*2], zfr[1][dc*2+1], dc == 0);
        if (dc < 2) EPI(pB, 13, dc);
    }
    // tile 15 (pB): chunks 60..63; drain 4 -> 4 -> 2 -> 0
    WAIT_VM(4); BAR(); STAGE(63);
    BODY(pB, 60, zfr[0][0], zfr[0][1], zfr[1][0], zfr[1][1], true);
    EPI(pA, 14, 0);
    WAIT_VM(4); BAR();
    BODY(pB, 61, zfr[0][2], zfr[0][3], zfr[1][2], zfr[1][3], false);
    EPI(pA, 14, 1);
    WAIT_VM(2); BAR();
    BODY(pB, 62, zfr[0][4], zfr[0][5], zfr[1][4], zfr[1][5], false);
    WAIT_VM(0); BAR();
    BODY(pB, 63, zfr[0][6], zfr[0][7], zfr[1][6], zfr[1][7], false);
    EPI(pB, 15, 0);
    EPI(pB, 15, 1);
    __syncthreads();

    // in-wave merge across the 4 lane-groups of each token: (mS,s,u) + top-2
    // (per-lane m2 starts at -inf; merging top-1 streams builds true top-2)
#pragma unroll
    for (int tf = 0; tf < 2; ++tf) {
#pragma unroll
        for (int off = 16; off <= 32; off <<= 1) {
            float om = __shfl_xor(mS[tf], off, 64);
            float os = __shfl_xor(sS[tf], off, 64);
            float ou = __shfl_xor(uU[tf], off, 64);
            float M = fmaxf(mS[tf], om);
            float da = mS[tf] - M, db = om - M;
            float ea = fexp2(da), eb = fexp2(db);
            uU[tf] = ea * (uU[tf] + sS[tf] * da) + eb * (ou + os * db);
            sS[tf] = ea * sS[tf] + eb * os;
            mS[tf] = M;
            float b1 = __shfl_xor(m1[tf], off, 64); int bi1 = __shfl_xor(i1[tf], off, 64);
            float b2 = __shfl_xor(m2[tf], off, 64); int bi2 = __shfl_xor(i2[tf], off, 64);
            bool bw = b1 > m1[tf];
            float hi2 = bw ? m1[tf] : b1; int hij = bw ? i1[tf] : bi1;
            float lo2 = bw ? b2 : m2[tf]; int loj = bw ? bi2 : i2[tf];
            m1[tf] = bw ? b1 : m1[tf]; i1[tf] = bw ? bi1 : i1[tf];
            bool s2w = lo2 > hi2;
            m2[tf] = s2w ? lo2 : hi2; i2[tf] = s2w ? loj : hij;
        }
    }

    // cross-wave (code-quarter) merge; 8 floats per (cg, token)
    float* sRed = (float*)sBuf;
    if (lane < 16) {
#pragma unroll
        for (int tf = 0; tf < 2; ++tf) {
            int t = tg * 32 + tf * 16 + lane;
            float* p = sRed + (cg * 64 + t) * 8;
            p[0] = mS[tf]; p[1] = sS[tf]; p[2] = uU[tf];
            p[3] = m1[tf]; p[4] = __int_as_float(i1[tf]);
            p[5] = m2[tf]; p[6] = __int_as_float(i2[tf]);
        }
    }
    __syncthreads();
    if (tid < 64) {
        const float* p0 = sRed + tid * 8;
        float am = p0[0], as_ = p0[1], au = p0[2];
        float a1 = p0[3], a2 = p0[5];
        int ai1 = __float_as_int(p0[4]), ai2 = __float_as_int(p0[6]);
#pragma unroll
        for (int w = 1; w < 4; ++w) {
            const float* pb = sRed + (w * 64 + tid) * 8;
            float bm = pb[0], bs = pb[1], bu = pb[2];
            float b1 = pb[3], b2 = pb[5];
            int bi1 = __float_as_int(pb[4]), bi2 = __float_as_int(pb[6]);
            float M = fmaxf(am, bm);
            float da = am - M, db = bm - M;
            float ea = fexp2(da), eb = fexp2(db);
            au = ea * (au + as_ * da) + eb * (bu + bs * db);
            as_ = ea * as_ + eb * bs;
            am = M;
            bool bw = b1 > a1;
            float hi2 = bw ? a1 : b1; int hij = bw ? ai1 : bi1;
            float lo2 = bw ? b2 : a2; int loj = bw ? bi2 : ai2;
            a1 = bw ? b1 : a1; ai1 = bw ? bi1 : ai1;
            bool s2w = lo2 > hi2;
            a2 = s2w ? lo2 : hi2; ai2 = s2w ? loj : hij;
        }
        int o = quarter * NTOK + tkbase + tid;
        pms[o] = am; psv[o] = as_; puv[o] = au; pi1[o] = ai1; pi2[o] = ai2;
    }
}

// ---------------------------------------------------------------- merge_quarters
__global__ __launch_bounds__(256) void merge_quarters(
    const float* __restrict__ pms, const float* __restrict__ psv, const float* __restrict__ puv,
    float* __restrict__ mls, float* __restrict__ samp)
{
    int n = blockIdx.x * 256 + threadIdx.x;
    float am = pms[n], as_ = psv[n], au = puv[n];
#pragma unroll
    for (int q = 1; q < NSPLIT; ++q) {
        float bm = pms[q * NTOK + n], bs = psv[q * NTOK + n], bu = puv[q * NTOK + n];
        float M = fmaxf(am, bm);
        float da = am - M, db = bm - M;
        float ea = fexp2(da), eb = fexp2(db);
        au = ea * (au + as_ * da) + eb * (bu + bs * db);
        as_ = ea * as_ + eb * bs;
        am = M;
    }
    float l2S = log2f(as_);
    mls[n] = am + l2S;                              // base-2 log-sum-exp2
    float plogp = LN2F * (au / as_ - l2S);          // natural-units sum p*logp
    __shared__ float red[256];
    red[threadIdx.x] = plogp;
    __syncthreads();
    for (int o = 128; o > 0; o >>= 1) {
        if (threadIdx.x < o) red[threadIdx.x] += red[threadIdx.x + o];
        __syncthreads();
    }
    if (threadIdx.x == 0) atomicAdd(samp, red[0]);
}

// ---------------------------------------------------------------- pass2
// avg_probs: 8 waves = 2 code-halves x 4 token-quarters of 128-token tiles.
// Each wave holds ITS 32 codes x 256 dims in regs; streams one token QUARTER.
// 4-deep counted-vmcnt ring; mls (base-2) staged in 8KB LDS. T15 pipeline.
__global__ __launch_bounds__(512, 4) void pass2(
    const f16* __restrict__ ef, const f16* __restrict__ zf,
    const float* __restrict__ mls, float* __restrict__ avgp)
{
    __shared__ __align__(16) char sBuf[4][16384];
    __shared__ float sMls[2048];

    const int tid = threadIdx.x;
    const int lane = tid & 63;
    const int wv = tid >> 6;
    const int ch = wv >> 2;        // code half (32 codes)
    const int tq = wv & 3;         // token quarter of the 128-token tile
    const int cbase = (int)(blockIdx.x >> 2) * 64;
    const int quarter = blockIdx.x & 3;
    const int nbase = quarter * NQ;

    f16x8 cfr[2][8];   // this wave's 32 codes x 256 dims

    {
        char* sb0 = (char*)sBuf;
#pragma unroll
        for (int i = 0; i < 4; ++i) {
            int row = wv * 8 + i * 2 + (lane >> 5);
            int chunk = (lane & 31) ^ (row & 7);
            gl16(ef + (size_t)(cbase + row) * DIMD + chunk * 8,
                 sb0 + wv * 4096 + i * 1024 + lane * 16);
        }
        *(float4*)&sMls[tid * 4] = *(const float4*)(mls + nbase + tid * 4);
        __syncthreads();
#pragma unroll
        for (int cf = 0; cf < 2; ++cf) {
            int row = ch * 32 + cf * 16 + (lane & 15);
#pragma unroll
            for (int ks = 0; ks < 8; ++ks) {
                int slot = (ks * 4 + (lane >> 4)) ^ (row & 7);
                cfr[cf][ks] = *(const f16x8*)(sb0 + row * 512 + slot * 16);
            }
        }
        __syncthreads();
    }

    const int rowZ0 = tq * 32 + (lane & 15);
    const int slotZ0 = (lane >> 4) ^ (lane & 7);
    const int slotZ1 = (4 + (lane >> 4)) ^ (lane & 7);
    const int offZ00 = rowZ0 * 128 + slotZ0 * 16;
    const int offZ01 = rowZ0 * 128 + slotZ1 * 16;
    const int offZ10 = offZ00 + 16 * 128;
    const int offZ11 = offZ01 + 16 * 128;
    const int dstLaneOff = wv * 2048 + lane * 16;
    const f16* zfBase = zf + (size_t)nbase * DIMD
                        + (size_t)(wv * 16 + (lane >> 3)) * DIMD
                        + ((lane & 7) ^ ((lane >> 3) & 7)) * 8;

    auto STAGE = [&](int c) {
        char* dst = (char*)sBuf + (c & 3) * 16384 + dstLaneOff;
        const f16* src = zfBase + (size_t)(c >> 2) * (128 * DIMD) + (c & 3) * 64;
        gl16(src, dst);
        gl16(src + 8 * DIMD, dst + 1024);
    };

    const f32x4 zero4 = {0.f, 0.f, 0.f, 0.f};
    f32x4 pA[2][2], pB[2][2];
    float av[2][4];
#pragma unroll
    for (int a = 0; a < 2; ++a)
#pragma unroll
        for (int r = 0; r < 4; ++r) av[a][r] = 0.f;

    auto BODY = [&](f32x4 (&A)[2][2], int c, f16x8 c00, f16x8 c01,
                    f16x8 c10, f16x8 c11, bool first) {
        const char* sb = (const char*)sBuf + (c & 3) * 16384;
        {
            f16x8 z0 = *(const f16x8*)(sb + offZ00);
            f16x8 z1 = *(const f16x8*)(sb + offZ10);
            A[0][0] = __builtin_amdgcn_mfma_f32_16x16x32_f16(c00, z0, first ? zero4 : A[0][0], 0, 0, 0);
            A[0][1] = __builtin_amdgcn_mfma_f32_16x16x32_f16(c00, z1, first ? zero4 : A[0][1], 0, 0, 0);
            A[1][0] = __builtin_amdgcn_mfma_f32_16x16x32_f16(c10, z0, first ? zero4 : A[1][0], 0, 0, 0);
            A[1][1] = __builtin_amdgcn_mfma_f32_16x16x32_f16(c10, z1, first ? zero4 : A[1][1], 0, 0, 0);
        }
        {
            f16x8 z0 = *(const f16x8*)(sb + offZ01);
            f16x8 z1 = *(const f16x8*)(sb + offZ11);
            A[0][0] = __builtin_amdgcn_mfma_f32_16x16x32_f16(c01, z0, A[0][0], 0, 0, 0);
            A[0][1] = __builtin_amdgcn_mfma_f32_16x16x32_f16(c01, z1, A[0][1], 0, 0, 0);
            A[1][0] = __builtin_amdgcn_mfma_f32_16x16x32_f16(c11, z0, A[1][0], 0, 0, 0);
            A[1][1] = __builtin_amdgcn_mfma_f32_16x16x32_f16(c11, z1, A[1][1], 0, 0, 0);
        }
    };

    // epilogue for ONE tokf of a completed tile's acc set
    auto EPI = [&](f32x4 (&A)[2][2], int tile, int tokf) {
        float mlsv = sMls[tile * 128 + tq * 32 + tokf * 16 + (lane & 15)];
#pragma unroll
        for (int cf = 0; cf < 2; ++cf)
#pragma unroll
            for (int r = 0; r < 4; ++r) {
                float x = fmaf(SCALE2, A[cf][tokf][r], -mlsv);
                av[cf][r] += fexp2(x);
            }
    };

    STAGE(0); STAGE(1); STAGE(2);

    for (int tp = 0; tp < 7; ++tp) {
        const int t0 = tp * 2, t1 = t0 + 1;
#pragma unroll
        for (int dc = 0; dc < 4; ++dc) {
            const int c = t0 * 4 + dc;
            WAIT_VM(4); BAR(); STAGE(c + 3);
            BODY(pA, c, cfr[0][dc*2], cfr[0][dc*2+1], cfr[1][dc*2], cfr[1][dc*2+1], dc == 0);
            if (tp > 0 && dc < 2) EPI(pB, t0 - 1, dc);
        }
#pragma unroll
        for (int dc = 0; dc < 4; ++dc) {
            const int c = t1 * 4 + dc;
            WAIT_VM(4); BAR(); STAGE(c + 3);
            BODY(pB, c, cfr[0][dc*2], cfr[0][dc*2+1], cfr[1][dc*2], cfr[1][dc*2+1], dc == 0);
            if (dc < 2) EPI(pA, t0, dc);
        }
    }
    // tile 14 (pA): chunks 56..59, STAGE 59..62
#pragma unroll
    for (int dc = 0; dc < 4; ++dc) {
        const int c = 56 + dc;
        WAIT_VM(4); BAR(); STAGE(c + 3);
        BODY(pA, c, cfr[0][dc*2], cfr[0][dc*2+1], cfr[1][dc*2], cfr[1][dc*2+1], dc == 0);
        if (dc < 2) EPI(pB, 13, dc);
    }
    // tile 15 (pB): chunks 60..63; drain
    WAIT_VM(4); BAR(); STAGE(63);
    BODY(pB, 60, cfr[0][0], cfr[0][1], cfr[1][0], cfr[1][1], true);
    EPI(pA, 14, 0);
    WAIT_VM(4); BAR();
    BODY(pB, 61, cfr[0][2], cfr[0][3], cfr[1][2], cfr[1][3], false);
    EPI(pA, 14, 1);
    WAIT_VM(2); BAR();
    BODY(pB, 62, cfr[0][4], cfr[0][5], cfr[1][4], cfr[1][5], false);
    WAIT_VM(0); BAR();
    BODY(pB, 63, cfr[0][6], cfr[0][7], cfr[1][6], cfr[1][7], false);
    EPI(pB, 15, 0);
    EPI(pB, 15, 1);
    __syncthreads();

    // reduce av over the 16 token-columns within each lane group
#pragma unroll
    for (int cf = 0; cf < 2; ++cf)
#pragma unroll
        for (int r = 0; r < 4; ++r) {
#pragma unroll
            for (int off = 1; off <= 8; off <<= 1)
                av[cf][r] += __shfl_xor(av[cf][r], off, 64);
        }
    float* sAv = (float*)sBuf;
    if ((lane & 15) == 0) {
#pragma unroll
        for (int cf = 0; cf < 2; ++cf)
#pragma unroll
            for (int r = 0; r < 4; ++r)
                sAv[wv * 32 + cf * 16 + (lane >> 4) * 4 + r] = av[cf][r];
    }
    __syncthreads();
    if (tid < 64) {
        int chh = tid >> 5;
        float s = 0.f;
#pragma unroll
        for (int w = 0; w < 4; ++w) s += sAv[(chh * 4 + w) * 32 + (tid & 31)];
        avgp[quarter * NCODE + cbase + tid] = s;
    }
}

// ---------------------------------------------------------------- fixup_gather
// Phase 1: per-token exact f32 argmin over 8 candidates (coalesced zn reads).
// Phase 2: gather z_q + vq sum for the block's 16 tokens.
__global__ __launch_bounds__(512) void fixup_gather(const float* __restrict__ z,
    const float* __restrict__ zn, const float* __restrict__ zinvp,
    const float* __restrict__ emb, const float* __restrict__ einvp,
    const float* __restrict__ esq,
    const int* __restrict__ pi1, const int* __restrict__ pi2,
    float* __restrict__ out, float* __restrict__ vq)
{
    __shared__ int sIdx[16];
    __shared__ float sRed[8];
    const int bh = blockIdx.x;
    const int tid = threadIdx.x;
    const int wv = tid >> 6, lane = tid & 63;
    const int b = bh >> 4, h = bh & 15;

    // ---- phase 1: fixup, 2 tokens per wave; zn rows are coalesced
#pragma unroll
    for (int rtok = 0; rtok < 2; ++rtok) {
        int n = bh * 16 + wv * 2 + rtok;
        int cand[8];
#pragma unroll
        for (int q = 0; q < NSPLIT; ++q) {
            cand[q * 2 + 0] = pi1[q * NTOK + n];
            cand[q * 2 + 1] = pi2[q * NTOK + n];
        }
        float dd[8];
#pragma unroll
        for (int k = 0; k < 8; ++k) dd[k] = 0.f;
        const float* znp = zn + (size_t)n * DIMD;
#pragma unroll
        for (int it = 0; it < 4; ++it) {
            int d = it * 64 + lane;
            float zv = znp[d];
#pragma unroll
            for (int k = 0; k < 8; ++k) dd[k] = fmaf(zv, emb[(size_t)cand[k] * 256 + d], dd[k]);
        }
#pragma unroll
        for (int off = 1; off < 64; off <<= 1) {
#pragma unroll
            for (int k = 0; k < 8; ++k) dd[k] += __shfl_xor(dd[k], off, 64);
        }
        if (lane == 0) {
            float bD = 3.0e38f; int bi = 0x7fffffff;
#pragma unroll
            for (int k = 0; k < 8; ++k) {
                float D = esq[cand[k]] - 2.f * dd[k] * einvp[cand[k]];
                bool win = (D < bD) || (D == bD && cand[k] < bi);
                bD = win ? D : bD; bi = win ? cand[k] : bi;
            }
            sIdx[wv * 2 + rtok] = bi;
        }
    }
    __syncthreads();

    // ---- phase 2: gather; thread handles channel c, w-range half*8..+7
    const int c = tid & 255;
    const int half = tid >> 8;
    const float* zp = z + (size_t)b * 65536 + (size_t)c * 256 + (size_t)h * 16 + half * 8;
    float buf[8];
    float sum = 0.f;
#pragma unroll
    for (int w = 0; w < 8; ++w) {
        int n = bh * 16 + half * 8 + w;
        int k = sIdx[half * 8 + w];
        float q  = emb[(size_t)k * DIMD + c] * einvp[k];
        float zv = zp[w] * zinvp[n];
        float d = q - zv;
        sum += d * d;
        buf[w] = q;
    }
    float* dst = out + (size_t)b * 65536 + (size_t)c * 256 + (size_t)h * 16 + half * 8;
    *(float4*)(dst + 0) = make_float4(buf[0], buf[1], buf[2], buf[3]);
    *(float4*)(dst + 4) = make_float4(buf[4], buf[5], buf[6], buf[7]);
#pragma unroll
    for (int o = 32; o > 0; o >>= 1) sum += __shfl_xor(sum, o, 64);
    if (lane == 0) sRed[wv] = sum;
    __syncthreads();
    if (tid == 0) {
        float s = 0.f;
#pragma unroll
        for (int w = 0; w < 8; ++w) s += sRed[w];
        atomicAdd(vq, s);
    }
}

// ---------------------------------------------------------------- finalize
__global__ __launch_bounds__(256) void finalize(const float* __restrict__ avgp,
    const float* __restrict__ scal, float* __restrict__ out3)
{
    int tid = threadIdx.x;
    float local = 0.f;
    for (int k = tid; k < NCODE; k += 256) {
        float a = 0.f;
#pragma unroll
        for (int q = 0; q < NSPLIT; ++q) a += avgp[q * NCODE + k];
        a *= (1.0f / 8192.0f);
        local += a * logf(a + 1e-5f);
    }
    __shared__ float red[256];
    red[tid] = local;
    __syncthreads();
    for (int o = 128; o > 0; o >>= 1) {
        if (tid < o) red[tid] += red[tid + o];
        __syncthreads();
    }
    if (tid == 0) {
        float avg_entropy = -red[0];
        float sample_entropy = -(scal[0] * (1.0f / 8192.0f));
        float ent = 0.1f * (sample_entropy - avg_entropy);
        float vql = scal[1] * (1.0f / 2097152.0f);
        out3[0] = vql;
        out3[1] = 0.25f * vql;
        out3[2] = ent;
    }
}

extern "C" void kernel_launch(void* const* d_in, const int* in_sizes, int n_in,
                              void* d_out, int out_size, void* d_ws, size_t ws_size,
                              hipStream_t stream)
{
    const float* z   = (const float*)d_in[0];
    const float* emb = (const float*)d_in[1];
    float* ws = (float*)d_ws;

    f16* zf16 = (f16*)ws;                      // 8192*256 f16 (4MB)
    f16* ef16 = (f16*)(ws + 1048576);          // 4MB
    float* zn   = ws + 2097152;                // 8192*256 f32 (8MB)
    float* esq  = zn + 2097152;                // 8192
    float* einv = esq + 8192;
    float* zinv = einv + 8192;
    float* avgp = zinv + 8192;                 // [4][8192]
    float* scal = avgp + NSPLIT * NCODE;       // [0]=sum p*logp, [1]=vq sum
    float* pms  = scal + 16;                   // [4][8192]
    int*   pi1  = (int*)(pms + 32768);
    int*   pi2  = (int*)(pi1 + 32768);
    float* psv  = (float*)(pi2 + 32768);
    float* puv  = psv + 32768;
    float* mls  = puv + 32768;                 // 8192 (base-2)

    float* outq = (float*)d_out;
    float* out3 = outq + 2097152;

    prep_all<<<2560, 256, 0, stream>>>(z, emb, zf16, zn, ef16, zinv, esq, einv, scal);
    pass1<<<512, 512, 0, stream>>>(ef16, zf16, pms, pi1, pi2, psv, puv);
    merge_quarters<<<32, 256, 0, stream>>>(pms, psv, puv, mls, scal);
    pass2<<<512, 512, 0, stream>>>(ef16, zf16, mls, avgp);
    fixup_gather<<<512, 512, 0, stream>>>(z, zn, zinv, emb, einv, esq, pi1, pi2, outq, scal + 1);
    finalize<<<1, 256, 0, stream>>>(avgp, scal, out3);
}

// Round 19
// 137.488 us; speedup vs baseline: 1.4498x; 1.4498x over previous
//
#include <hip/hip_runtime.h>
#include <math.h>

#define NTOK 8192
#define NCODE 8192
#define DIMD 256
#define NSPLIT 4
#define KQ (NCODE / NSPLIT)     // 2048 codes per pass1 quarter
#define NQ (NTOK / NSPLIT)      // 2048 tokens per pass2 quarter
#define SCALE2 288.5390081777927f   // 200 * log2(e)
#define LN2F 0.6931471805599453f

typedef _Float16 f16;
typedef _Float16 f16x8 __attribute__((ext_vector_type(8)));
typedef float f32x4 __attribute__((ext_vector_type(4)));

#define WAIT_VM(N) asm volatile("s_waitcnt vmcnt(" #N ")" ::: "memory")
#define BAR() __builtin_amdgcn_s_barrier()

__device__ __forceinline__ float fexp2(float x) {
    return __builtin_amdgcn_exp2f(x);   // v_exp_f32 (2^x)
}
__device__ __forceinline__ float4 ldg4(const float* p) {
    return *reinterpret_cast<const float4*>(p);
}
__device__ __forceinline__ unsigned short f2h(float x) {
    f16 h = (f16)x;
    return __builtin_bit_cast(unsigned short, h);
}
__device__ __forceinline__ void gl16(const void* g, void* l) {
    __builtin_amdgcn_global_load_lds(
        (const __attribute__((address_space(1))) unsigned int*)g,
        (__attribute__((address_space(3))) unsigned int*)l, 16, 0, 0);
}

// ---------------------------------------------------------------- prep_all
// blocks 0..511: normalize z -> zf16 + zn (f32) + zinv ; 512..2559: embedding
__global__ __launch_bounds__(256) void prep_all(const float* __restrict__ z,
    const float* __restrict__ e, f16* __restrict__ zf, float* __restrict__ zn,
    f16* __restrict__ ef, float* __restrict__ zinvp, float* __restrict__ esq,
    float* __restrict__ einvp, float* __restrict__ scal)
{
    if (blockIdx.x < 512) {
        int bh = blockIdx.x;
        int c  = threadIdx.x;
        const float* src = z + (size_t)(bh >> 4) * 65536 + (size_t)c * 256 + (size_t)(bh & 15) * 16;
        float v[16];
        float4 t0 = ldg4(src + 0), t1 = ldg4(src + 4), t2 = ldg4(src + 8), t3 = ldg4(src + 12);
        v[0]=t0.x; v[1]=t0.y; v[2]=t0.z; v[3]=t0.w;
        v[4]=t1.x; v[5]=t1.y; v[6]=t1.z; v[7]=t1.w;
        v[8]=t2.x; v[9]=t2.y; v[10]=t2.z; v[11]=t2.w;
        v[12]=t3.x; v[13]=t3.y; v[14]=t3.z; v[15]=t3.w;
        float sq[16];
#pragma unroll
        for (int w = 0; w < 16; ++w) sq[w] = v[w] * v[w];
#pragma unroll
        for (int o = 32; o > 0; o >>= 1) {
#pragma unroll
            for (int w = 0; w < 16; ++w) sq[w] += __shfl_xor(sq[w], o, 64);
        }
        __shared__ float part[4][16];
        __shared__ float invS[16];
        int wave = c >> 6, lane = c & 63;
        if (lane == 0) {
#pragma unroll
            for (int w = 0; w < 16; ++w) part[wave][w] = sq[w];
        }
        __syncthreads();
        if (c < 16) {
            float s = part[0][c] + part[1][c] + part[2][c] + part[3][c];
            float iv = 1.0f / sqrtf(s + 1e-12f);
            invS[c] = iv;
            zinvp[bh * 16 + c] = iv;
        }
        __syncthreads();
#pragma unroll
        for (int w = 0; w < 16; ++w) {
            float nv = v[w] * invS[w];
            zf[(size_t)(bh * 16 + w) * DIMD + c] = (f16)nv;
            zn[(size_t)(bh * 16 + w) * DIMD + c] = nv;
        }
    } else {
        if (blockIdx.x == 512 && threadIdx.x < 2) scal[threadIdx.x] = 0.0f;
        int row  = (int)(blockIdx.x - 512) * 4 + (threadIdx.x >> 6);
        int lane = threadIdx.x & 63;
        float4 v = ldg4(e + (size_t)row * DIMD + lane * 4);
        float ss = v.x*v.x + v.y*v.y + v.z*v.z + v.w*v.w;
#pragma unroll
        for (int o = 32; o > 0; o >>= 1) ss += __shfl_xor(ss, o, 64);
        float inv = 1.0f / sqrtf(ss + 1e-12f);
        float w4[4] = { v.x*inv, v.y*inv, v.z*inv, v.w*inv };
        ushort4 pk;
        pk.x = f2h(w4[0]); pk.y = f2h(w4[1]); pk.z = f2h(w4[2]); pk.w = f2h(w4[3]);
        *reinterpret_cast<ushort4*>(ef + (size_t)row * DIMD + lane * 4) = pk;
        float s2 = w4[0]*w4[0] + w4[1]*w4[1] + w4[2]*w4[2] + w4[3]*w4[3];
#pragma unroll
        for (int o = 32; o > 0; o >>= 1) s2 += __shfl_xor(s2, o, 64);
        if (lane == 0) { esq[row] = s2; einvp[row] = inv; }
    }
}

// ---------------------------------------------------------------- pass1
// D[code][token] f16 MFMA GEMM. Base-2 logits (esq dropped from ranking;
// fixup exact). Per-lane online softmax (defer-max THR=40) + per-lane TOP-1.
// 4-slot LDS ring (64KB, 3 chunks in flight), counted vmcnt(4).
// dc==0 chunk feeds C=0 into MFMA (no epilogue re-zeroing).
__global__ __launch_bounds__(512, 4) void pass1(
    const f16* __restrict__ ef, const f16* __restrict__ zf,
    float* __restrict__ pms, int* __restrict__ pi1, int* __restrict__ pi2,
    float* __restrict__ psv, float* __restrict__ puv)
{
    __shared__ __align__(16) char sBuf[4][16384];

    const int tid = threadIdx.x;
    const int lane = tid & 63;
    const int wv = tid >> 6;
    const int tg = wv >> 2;        // token half (32 tokens)
    const int cg = wv & 3;         // code quarter of the 128-code tile
    const int tkbase = (int)(blockIdx.x >> 2) * 64;
    const int quarter = blockIdx.x & 3;
    const int kbase = quarter * KQ;

    f16x8 zfr[2][8];   // this wave's 32 tokens x 256 dims (64 VGPR)

    // ---- prologue: stage 64 tokens (swizzled 32KB = slots 0,1), read own half
    {
        char* sb0 = (char*)sBuf;
#pragma unroll
        for (int i = 0; i < 4; ++i) {
            int row = wv * 8 + i * 2 + (lane >> 5);
            int chunk = (lane & 31) ^ (row & 7);
            gl16(zf + (size_t)(tkbase + row) * DIMD + chunk * 8,
                 sb0 + wv * 4096 + i * 1024 + lane * 16);
        }
        __syncthreads();
#pragma unroll
        for (int tf = 0; tf < 2; ++tf) {
            int row = tg * 32 + tf * 16 + (lane & 15);
#pragma unroll
            for (int ks = 0; ks < 8; ++ks) {
                int slot = (ks * 4 + (lane >> 4)) ^ (row & 7);
                zfr[tf][ks] = *(const f16x8*)(sb0 + row * 512 + slot * 16);
            }
        }
        __syncthreads();
    }

    // hoisted loop-invariant offsets
    const int rowE0 = cg * 32 + (lane & 15);
    const int slotE0 = (lane >> 4) ^ (lane & 7);
    const int slotE1 = (4 + (lane >> 4)) ^ (lane & 7);
    const int offE00 = rowE0 * 128 + slotE0 * 16;
    const int offE01 = rowE0 * 128 + slotE1 * 16;
    const int offE10 = offE00 + 16 * 128;
    const int offE11 = offE01 + 16 * 128;
    const int dstLaneOff = wv * 2048 + lane * 16;
    const f16* efBase = ef + (size_t)kbase * DIMD
                        + (size_t)(wv * 16 + (lane >> 3)) * DIMD
                        + ((lane & 7) ^ ((lane >> 3) & 7)) * 8;

    auto STAGE = [&](int c) {
        char* dst = (char*)sBuf + (c & 3) * 16384 + dstLaneOff;
        const f16* src = efBase + (size_t)(c >> 2) * (128 * DIMD) + (c & 3) * 64;
        gl16(src, dst);
        gl16(src + 8 * DIMD, dst + 1024);
    };

    const f32x4 zero4 = {0.f, 0.f, 0.f, 0.f};
    f32x4 acc[2][2];
#pragma unroll
    for (int a = 0; a < 2; ++a)
#pragma unroll
        for (int b = 0; b < 2; ++b) acc[a][b] = zero4;

    // per-lane state: softmax ref mS (base-2, defer-max), s,u; top-1 raw-dot
    float mS[2], sS[2], uU[2], m1[2], m2[2];
    int i1[2], i2[2];
#pragma unroll
    for (int t = 0; t < 2; ++t) {
        mS[t] = -3.0e38f; sS[t] = 0.f; uU[t] = 0.f;
        m1[t] = -3.0e38f; m2[t] = -3.0e38f; i1[t] = 0; i2[t] = 0;
    }

    auto BODY = [&](int c, f16x8 z00, f16x8 z01, f16x8 z10, f16x8 z11,
                    bool first, bool epi) {
        const char* sb = (const char*)sBuf + (c & 3) * 16384;
        {
            f16x8 e0 = *(const f16x8*)(sb + offE00);
            f16x8 e1 = *(const f16x8*)(sb + offE10);
            acc[0][0] = __builtin_amdgcn_mfma_f32_16x16x32_f16(e0, z00, first ? zero4 : acc[0][0], 0, 0, 0);
            acc[0][1] = __builtin_amdgcn_mfma_f32_16x16x32_f16(e0, z10, first ? zero4 : acc[0][1], 0, 0, 0);
            acc[1][0] = __builtin_amdgcn_mfma_f32_16x16x32_f16(e1, z00, first ? zero4 : acc[1][0], 0, 0, 0);
            acc[1][1] = __builtin_amdgcn_mfma_f32_16x16x32_f16(e1, z10, first ? zero4 : acc[1][1], 0, 0, 0);
        }
        {
            f16x8 e0 = *(const f16x8*)(sb + offE01);
            f16x8 e1 = *(const f16x8*)(sb + offE11);
            acc[0][0] = __builtin_amdgcn_mfma_f32_16x16x32_f16(e0, z01, acc[0][0], 0, 0, 0);
            acc[0][1] = __builtin_amdgcn_mfma_f32_16x16x32_f16(e0, z11, acc[0][1], 0, 0, 0);
            acc[1][0] = __builtin_amdgcn_mfma_f32_16x16x32_f16(e1, z01, acc[1][0], 0, 0, 0);
            acc[1][1] = __builtin_amdgcn_mfma_f32_16x16x32_f16(e1, z11, acc[1][1], 0, 0, 0);
        }
        if (epi) {
            // -------- per-lane epilogue for this 128-code tile --------
            const int tile = c >> 2;
            const int codeB = kbase + tile * 128 + cg * 32 + (lane >> 4) * 4;
#pragma unroll
            for (int tf = 0; tf < 2; ++tf) {
                // top-1 insert on RAW dots (monotone in logit)
#pragma unroll
                for (int j = 0; j < 8; ++j) {
                    float x = acc[j >> 2][tf][j & 3];
                    int cid = codeB + (j >> 2) * 16 + (j & 3);
                    bool c1 = x > m1[tf];
                    i1[tf] = c1 ? cid : i1[tf];
                    m1[tf] = c1 ? x : m1[tf];
                }
                // defer-max guard (base-2 units)
                float l2 = SCALE2 * m1[tf];
                if (l2 > mS[tf] + 40.f) {
                    float dm = mS[tf] - l2;
                    float al = fexp2(dm);
                    uU[tf] = al * (uU[tf] + sS[tf] * dm);
                    sS[tf] = al * sS[tf];
                    mS[tf] = l2;
                }
                float ps = 0.f, pu = 0.f;
                float nm = -mS[tf];
#pragma unroll
                for (int j = 0; j < 8; ++j) {
                    float xm = fmaf(SCALE2, acc[j >> 2][tf][j & 3], nm);
                    float e2 = fexp2(xm);
                    ps += e2;
                    pu = fmaf(e2, xm, pu);
                }
                sS[tf] += ps;
                uU[tf] += pu;
            }
        }
    };

    STAGE(0); STAGE(1); STAGE(2);

    for (int tile = 0; tile < 15; ++tile) {
#pragma unroll
        for (int dc = 0; dc < 4; ++dc) {
            const int c = tile * 4 + dc;
            WAIT_VM(4);              // chunk c complete; c+1,c+2 in flight
            BAR();
            STAGE(c + 3);            // slot (c+3)&3 last read in BODY(c-1): safe
            BODY(c, zfr[0][dc*2], zfr[0][dc*2+1], zfr[1][dc*2], zfr[1][dc*2+1],
                 dc == 0, dc == 3);
        }
    }
    // tail: tile 15 (chunks 60..63), drain 4 -> 4 -> 2 -> 0
    WAIT_VM(4); BAR(); STAGE(63);
    BODY(60, zfr[0][0], zfr[0][1], zfr[1][0], zfr[1][1], true, false);
    WAIT_VM(4); BAR();
    BODY(61, zfr[0][2], zfr[0][3], zfr[1][2], zfr[1][3], false, false);
    WAIT_VM(2); BAR();
    BODY(62, zfr[0][4], zfr[0][5], zfr[1][4], zfr[1][5], false, false);
    WAIT_VM(0); BAR();
    BODY(63, zfr[0][6], zfr[0][7], zfr[1][6], zfr[1][7], false, true);
    __syncthreads();

    // in-wave merge across the 4 lane-groups of each token: (mS,s,u) + top-2
    // (per-lane m2 starts at -inf; merging top-1 streams builds true top-2)
#pragma unroll
    for (int tf = 0; tf < 2; ++tf) {
#pragma unroll
        for (int off = 16; off <= 32; off <<= 1) {
            float om = __shfl_xor(mS[tf], off, 64);
            float os = __shfl_xor(sS[tf], off, 64);
            float ou = __shfl_xor(uU[tf], off, 64);
            float M = fmaxf(mS[tf], om);
            float da = mS[tf] - M, db = om - M;
            float ea = fexp2(da), eb = fexp2(db);
            uU[tf] = ea * (uU[tf] + sS[tf] * da) + eb * (ou + os * db);
            sS[tf] = ea * sS[tf] + eb * os;
            mS[tf] = M;
            float b1 = __shfl_xor(m1[tf], off, 64); int bi1 = __shfl_xor(i1[tf], off, 64);
            float b2 = __shfl_xor(m2[tf], off, 64); int bi2 = __shfl_xor(i2[tf], off, 64);
            bool bw = b1 > m1[tf];
            float hi2 = bw ? m1[tf] : b1; int hij = bw ? i1[tf] : bi1;
            float lo2 = bw ? b2 : m2[tf]; int loj = bw ? bi2 : i2[tf];
            m1[tf] = bw ? b1 : m1[tf]; i1[tf] = bw ? bi1 : i1[tf];
            bool s2w = lo2 > hi2;
            m2[tf] = s2w ? lo2 : hi2; i2[tf] = s2w ? loj : hij;
        }
    }

    // cross-wave (code-quarter) merge; 8 floats per (cg, token)
    float* sRed = (float*)sBuf;
    if (lane < 16) {
#pragma unroll
        for (int tf = 0; tf < 2; ++tf) {
            int t = tg * 32 + tf * 16 + lane;
            float* p = sRed + (cg * 64 + t) * 8;
            p[0] = mS[tf]; p[1] = sS[tf]; p[2] = uU[tf];
            p[3] = m1[tf]; p[4] = __int_as_float(i1[tf]);
            p[5] = m2[tf]; p[6] = __int_as_float(i2[tf]);
        }
    }
    __syncthreads();
    if (tid < 64) {
        const float* p0 = sRed + tid * 8;
        float am = p0[0], as_ = p0[1], au = p0[2];
        float a1 = p0[3], a2 = p0[5];
        int ai1 = __float_as_int(p0[4]), ai2 = __float_as_int(p0[6]);
#pragma unroll
        for (int w = 1; w < 4; ++w) {
            const float* pb = sRed + (w * 64 + tid) * 8;
            float bm = pb[0], bs = pb[1], bu = pb[2];
            float b1 = pb[3], b2 = pb[5];
            int bi1 = __float_as_int(pb[4]), bi2 = __float_as_int(pb[6]);
            float M = fmaxf(am, bm);
            float da = am - M, db = bm - M;
            float ea = fexp2(da), eb = fexp2(db);
            au = ea * (au + as_ * da) + eb * (bu + bs * db);
            as_ = ea * as_ + eb * bs;
            am = M;
            bool bw = b1 > a1;
            float hi2 = bw ? a1 : b1; int hij = bw ? ai1 : bi1;
            float lo2 = bw ? b2 : a2; int loj = bw ? bi2 : ai2;
            a1 = bw ? b1 : a1; ai1 = bw ? bi1 : ai1;
            bool s2w = lo2 > hi2;
            a2 = s2w ? lo2 : hi2; ai2 = s2w ? loj : hij;
        }
        int o = quarter * NTOK + tkbase + tid;
        pms[o] = am; psv[o] = as_; puv[o] = au; pi1[o] = ai1; pi2[o] = ai2;
    }
}

// ---------------------------------------------------------------- merge_quarters
__global__ __launch_bounds__(256) void merge_quarters(
    const float* __restrict__ pms, const float* __restrict__ psv, const float* __restrict__ puv,
    float* __restrict__ mls, float* __restrict__ samp)
{
    int n = blockIdx.x * 256 + threadIdx.x;
    float am = pms[n], as_ = psv[n], au = puv[n];
#pragma unroll
    for (int q = 1; q < NSPLIT; ++q) {
        float bm = pms[q * NTOK + n], bs = psv[q * NTOK + n], bu = puv[q * NTOK + n];
        float M = fmaxf(am, bm);
        float da = am - M, db = bm - M;
        float ea = fexp2(da), eb = fexp2(db);
        au = ea * (au + as_ * da) + eb * (bu + bs * db);
        as_ = ea * as_ + eb * bs;
        am = M;
    }
    float l2S = log2f(as_);
    mls[n] = am + l2S;                              // base-2 log-sum-exp2
    float plogp = LN2F * (au / as_ - l2S);          // natural-units sum p*logp
    __shared__ float red[256];
    red[threadIdx.x] = plogp;
    __syncthreads();
    for (int o = 128; o > 0; o >>= 1) {
        if (threadIdx.x < o) red[threadIdx.x] += red[threadIdx.x + o];
        __syncthreads();
    }
    if (threadIdx.x == 0) atomicAdd(samp, red[0]);
}

// ---------------------------------------------------------------- pass2
// avg_probs: 8 waves = 2 code-halves x 4 token-quarters of 128-token tiles.
// Each wave holds ITS 32 codes x 256 dims in regs; streams one token QUARTER.
// 4-deep counted-vmcnt ring; mls (base-2) staged in 8KB LDS. 72KB total.
__global__ __launch_bounds__(512, 4) void pass2(
    const f16* __restrict__ ef, const f16* __restrict__ zf,
    const float* __restrict__ mls, float* __restrict__ avgp)
{
    __shared__ __align__(16) char sBuf[4][16384];
    __shared__ float sMls[2048];

    const int tid = threadIdx.x;
    const int lane = tid & 63;
    const int wv = tid >> 6;
    const int ch = wv >> 2;        // code half (32 codes)
    const int tq = wv & 3;         // token quarter of the 128-token tile
    const int cbase = (int)(blockIdx.x >> 2) * 64;
    const int quarter = blockIdx.x & 3;
    const int nbase = quarter * NQ;

    f16x8 cfr[2][8];   // this wave's 32 codes x 256 dims

    {
        char* sb0 = (char*)sBuf;
#pragma unroll
        for (int i = 0; i < 4; ++i) {
            int row = wv * 8 + i * 2 + (lane >> 5);
            int chunk = (lane & 31) ^ (row & 7);
            gl16(ef + (size_t)(cbase + row) * DIMD + chunk * 8,
                 sb0 + wv * 4096 + i * 1024 + lane * 16);
        }
        *(float4*)&sMls[tid * 4] = *(const float4*)(mls + nbase + tid * 4);
        __syncthreads();
#pragma unroll
        for (int cf = 0; cf < 2; ++cf) {
            int row = ch * 32 + cf * 16 + (lane & 15);
#pragma unroll
            for (int ks = 0; ks < 8; ++ks) {
                int slot = (ks * 4 + (lane >> 4)) ^ (row & 7);
                cfr[cf][ks] = *(const f16x8*)(sb0 + row * 512 + slot * 16);
            }
        }
        __syncthreads();
    }

    const int rowZ0 = tq * 32 + (lane & 15);
    const int slotZ0 = (lane >> 4) ^ (lane & 7);
    const int slotZ1 = (4 + (lane >> 4)) ^ (lane & 7);
    const int offZ00 = rowZ0 * 128 + slotZ0 * 16;
    const int offZ01 = rowZ0 * 128 + slotZ1 * 16;
    const int offZ10 = offZ00 + 16 * 128;
    const int offZ11 = offZ01 + 16 * 128;
    const int dstLaneOff = wv * 2048 + lane * 16;
    const f16* zfBase = zf + (size_t)nbase * DIMD
                        + (size_t)(wv * 16 + (lane >> 3)) * DIMD
                        + ((lane & 7) ^ ((lane >> 3) & 7)) * 8;

    auto STAGE = [&](int c) {
        char* dst = (char*)sBuf + (c & 3) * 16384 + dstLaneOff;
        const f16* src = zfBase + (size_t)(c >> 2) * (128 * DIMD) + (c & 3) * 64;
        gl16(src, dst);
        gl16(src + 8 * DIMD, dst + 1024);
    };

    const f32x4 zero4 = {0.f, 0.f, 0.f, 0.f};
    f32x4 acc[2][2];
#pragma unroll
    for (int a = 0; a < 2; ++a)
#pragma unroll
        for (int b = 0; b < 2; ++b) acc[a][b] = zero4;
    float av[2][4];
#pragma unroll
    for (int a = 0; a < 2; ++a)
#pragma unroll
        for (int r = 0; r < 4; ++r) av[a][r] = 0.f;

    auto BODY = [&](int c, f16x8 c00, f16x8 c01, f16x8 c10, f16x8 c11,
                    bool first, bool epi) {
        const char* sb = (const char*)sBuf + (c & 3) * 16384;
        {
            f16x8 z0 = *(const f16x8*)(sb + offZ00);
            f16x8 z1 = *(const f16x8*)(sb + offZ10);
            acc[0][0] = __builtin_amdgcn_mfma_f32_16x16x32_f16(c00, z0, first ? zero4 : acc[0][0], 0, 0, 0);
            acc[0][1] = __builtin_amdgcn_mfma_f32_16x16x32_f16(c00, z1, first ? zero4 : acc[0][1], 0, 0, 0);
            acc[1][0] = __builtin_amdgcn_mfma_f32_16x16x32_f16(c10, z0, first ? zero4 : acc[1][0], 0, 0, 0);
            acc[1][1] = __builtin_amdgcn_mfma_f32_16x16x32_f16(c10, z1, first ? zero4 : acc[1][1], 0, 0, 0);
        }
        {
            f16x8 z0 = *(const f16x8*)(sb + offZ01);
            f16x8 z1 = *(const f16x8*)(sb + offZ11);
            acc[0][0] = __builtin_amdgcn_mfma_f32_16x16x32_f16(c01, z0, acc[0][0], 0, 0, 0);
            acc[0][1] = __builtin_amdgcn_mfma_f32_16x16x32_f16(c01, z1, acc[0][1], 0, 0, 0);
            acc[1][0] = __builtin_amdgcn_mfma_f32_16x16x32_f16(c11, z0, acc[1][0], 0, 0, 0);
            acc[1][1] = __builtin_amdgcn_mfma_f32_16x16x32_f16(c11, z1, acc[1][1], 0, 0, 0);
        }
        if (epi) {
            const int tile = c >> 2;
            float mlsv[2];
            mlsv[0] = sMls[tile * 128 + tq * 32 + (lane & 15)];
            mlsv[1] = sMls[tile * 128 + tq * 32 + 16 + (lane & 15)];
#pragma unroll
            for (int cf = 0; cf < 2; ++cf)
#pragma unroll
                for (int tokf = 0; tokf < 2; ++tokf) {
#pragma unroll
                    for (int r = 0; r < 4; ++r) {
                        float x = fmaf(SCALE2, acc[cf][tokf][r], -mlsv[tokf]);
                        av[cf][r] += fexp2(x);
                    }
                }
        }
    };

    STAGE(0); STAGE(1); STAGE(2);

    for (int tile = 0; tile < 15; ++tile) {
#pragma unroll
        for (int dc = 0; dc < 4; ++dc) {
            const int c = tile * 4 + dc;
            WAIT_VM(4);
            BAR();
            STAGE(c + 3);
            BODY(c, cfr[0][dc*2], cfr[0][dc*2+1], cfr[1][dc*2], cfr[1][dc*2+1],
                 dc == 0, dc == 3);
        }
    }
    WAIT_VM(4); BAR(); STAGE(63);
    BODY(60, cfr[0][0], cfr[0][1], cfr[1][0], cfr[1][1], true, false);
    WAIT_VM(4); BAR();
    BODY(61, cfr[0][2], cfr[0][3], cfr[1][2], cfr[1][3], false, false);
    WAIT_VM(2); BAR();
    BODY(62, cfr[0][4], cfr[0][5], cfr[1][4], cfr[1][5], false, false);
    WAIT_VM(0); BAR();
    BODY(63, cfr[0][6], cfr[0][7], cfr[1][6], cfr[1][7], false, true);
    __syncthreads();

    // reduce av over the 16 token-columns within each lane group
#pragma unroll
    for (int cf = 0; cf < 2; ++cf)
#pragma unroll
        for (int r = 0; r < 4; ++r) {
#pragma unroll
            for (int off = 1; off <= 8; off <<= 1)
                av[cf][r] += __shfl_xor(av[cf][r], off, 64);
        }
    float* sAv = (float*)sBuf;
    if ((lane & 15) == 0) {
#pragma unroll
        for (int cf = 0; cf < 2; ++cf)
#pragma unroll
            for (int r = 0; r < 4; ++r)
                sAv[wv * 32 + cf * 16 + (lane >> 4) * 4 + r] = av[cf][r];
    }
    __syncthreads();
    if (tid < 64) {
        int chh = tid >> 5;
        float s = 0.f;
#pragma unroll
        for (int w = 0; w < 4; ++w) s += sAv[(chh * 4 + w) * 32 + (tid & 31)];
        avgp[quarter * NCODE + cbase + tid] = s;
    }
}

// ---------------------------------------------------------------- fixup_gather
// Phase 1: per-token exact f32 argmin over 8 candidates (coalesced zn reads).
// Phase 2: gather z_q + vq sum for the block's 16 tokens.
__global__ __launch_bounds__(512) void fixup_gather(const float* __restrict__ z,
    const float* __restrict__ zn, const float* __restrict__ zinvp,
    const float* __restrict__ emb, const float* __restrict__ einvp,
    const float* __restrict__ esq,
    const int* __restrict__ pi1, const int* __restrict__ pi2,
    float* __restrict__ out, float* __restrict__ vq)
{
    __shared__ int sIdx[16];
    __shared__ float sRed[8];
    const int bh = blockIdx.x;
    const int tid = threadIdx.x;
    const int wv = tid >> 6, lane = tid & 63;
    const int b = bh >> 4, h = bh & 15;

    // ---- phase 1: fixup, 2 tokens per wave; zn rows are coalesced
#pragma unroll
    for (int rtok = 0; rtok < 2; ++rtok) {
        int n = bh * 16 + wv * 2 + rtok;
        int cand[8];
#pragma unroll
        for (int q = 0; q < NSPLIT; ++q) {
            cand[q * 2 + 0] = pi1[q * NTOK + n];
            cand[q * 2 + 1] = pi2[q * NTOK + n];
        }
        float dd[8];
#pragma unroll
        for (int k = 0; k < 8; ++k) dd[k] = 0.f;
        const float* znp = zn + (size_t)n * DIMD;
#pragma unroll
        for (int it = 0; it < 4; ++it) {
            int d = it * 64 + lane;
            float zv = znp[d];
#pragma unroll
            for (int k = 0; k < 8; ++k) dd[k] = fmaf(zv, emb[(size_t)cand[k] * 256 + d], dd[k]);
        }
#pragma unroll
        for (int off = 1; off < 64; off <<= 1) {
#pragma unroll
            for (int k = 0; k < 8; ++k) dd[k] += __shfl_xor(dd[k], off, 64);
        }
        if (lane == 0) {
            float bD = 3.0e38f; int bi = 0x7fffffff;
#pragma unroll
            for (int k = 0; k < 8; ++k) {
                float D = esq[cand[k]] - 2.f * dd[k] * einvp[cand[k]];
                bool win = (D < bD) || (D == bD && cand[k] < bi);
                bD = win ? D : bD; bi = win ? cand[k] : bi;
            }
            sIdx[wv * 2 + rtok] = bi;
        }
    }
    __syncthreads();

    // ---- phase 2: gather; thread handles channel c, w-range half*8..+7
    const int c = tid & 255;
    const int half = tid >> 8;
    const float* zp = z + (size_t)b * 65536 + (size_t)c * 256 + (size_t)h * 16 + half * 8;
    float buf[8];
    float sum = 0.f;
#pragma unroll
    for (int w = 0; w < 8; ++w) {
        int n = bh * 16 + half * 8 + w;
        int k = sIdx[half * 8 + w];
        float q  = emb[(size_t)k * DIMD + c] * einvp[k];
        float zv = zp[w] * zinvp[n];
        float d = q - zv;
        sum += d * d;
        buf[w] = q;
    }
    float* dst = out + (size_t)b * 65536 + (size_t)c * 256 + (size_t)h * 16 + half * 8;
    *(float4*)(dst + 0) = make_float4(buf[0], buf[1], buf[2], buf[3]);
    *(float4*)(dst + 4) = make_float4(buf[4], buf[5], buf[6], buf[7]);
#pragma unroll
    for (int o = 32; o > 0; o >>= 1) sum += __shfl_xor(sum, o, 64);
    if (lane == 0) sRed[wv] = sum;
    __syncthreads();
    if (tid == 0) {
        float s = 0.f;
#pragma unroll
        for (int w = 0; w < 8; ++w) s += sRed[w];
        atomicAdd(vq, s);
    }
}

// ---------------------------------------------------------------- finalize
__global__ __launch_bounds__(256) void finalize(const float* __restrict__ avgp,
    const float* __restrict__ scal, float* __restrict__ out3)
{
    int tid = threadIdx.x;
    float local = 0.f;
    for (int k = tid; k < NCODE; k += 256) {
        float a = 0.f;
#pragma unroll
        for (int q = 0; q < NSPLIT; ++q) a += avgp[q * NCODE + k];
        a *= (1.0f / 8192.0f);
        local += a * logf(a + 1e-5f);
    }
    __shared__ float red[256];
    red[tid] = local;
    __syncthreads();
    for (int o = 128; o > 0; o >>= 1) {
        if (tid < o) red[tid] += red[tid + o];
        __syncthreads();
    }
    if (tid == 0) {
        float avg_entropy = -red[0];
        float sample_entropy = -(scal[0] * (1.0f / 8192.0f));
        float ent = 0.1f * (sample_entropy - avg_entropy);
        float vql = scal[1] * (1.0f / 2097152.0f);
        out3[0] = vql;
        out3[1] = 0.25f * vql;
        out3[2] = ent;
    }
}

extern "C" void kernel_launch(void* const* d_in, const int* in_sizes, int n_in,
                              void* d_out, int out_size, void* d_ws, size_t ws_size,
                              hipStream_t stream)
{
    const float* z   = (const float*)d_in[0];
    const float* emb = (const float*)d_in[1];
    float* ws = (float*)d_ws;

    f16* zf16 = (f16*)ws;                      // 8192*256 f16 (4MB)
    f16* ef16 = (f16*)(ws + 1048576);          // 4MB
    float* zn   = ws + 2097152;                // 8192*256 f32 (8MB)
    float* esq  = zn + 2097152;                // 8192
    float* einv = esq + 8192;
    float* zinv = einv + 8192;
    float* avgp = zinv + 8192;                 // [4][8192]
    float* scal = avgp + NSPLIT * NCODE;       // [0]=sum p*logp, [1]=vq sum
    float* pms  = scal + 16;                   // [4][8192]
    int*   pi1  = (int*)(pms + 32768);
    int*   pi2  = (int*)(pi1 + 32768);
    float* psv  = (float*)(pi2 + 32768);
    float* puv  = psv + 32768;
    float* mls  = puv + 32768;                 // 8192 (base-2)

    float* outq = (float*)d_out;
    float* out3 = outq + 2097152;

    prep_all<<<2560, 256, 0, stream>>>(z, emb, zf16, zn, ef16, zinv, esq, einv, scal);
    pass1<<<512, 512, 0, stream>>>(ef16, zf16, pms, pi1, pi2, psv, puv);
    merge_quarters<<<32, 256, 0, stream>>>(pms, psv, puv, mls, scal);
    pass2<<<512, 512, 0, stream>>>(ef16, zf16, mls, avgp);
    fixup_gather<<<512, 512, 0, stream>>>(z, zn, zinv, emb, einv, esq, pi1, pi2, outq, scal + 1);
    finalize<<<1, 256, 0, stream>>>(avgp, scal, out3);
}